// Round 1
// baseline (359.653 us; speedup 1.0000x reference)
//
#include <hip/hip_runtime.h>

#define NN 25000
#define EE 400000
#define FIN 128
#define FE 16
#define CH 32
#define SLOPE 0.01f

// leaky_relu(x) = max(x, 0.01x)  (valid since 0.01x >= x iff x <= 0)
__device__ __forceinline__ float lrelu(float v) { return fmaxf(v, SLOPE * v); }

// ---------------- Kernel 1: h = leaky(x @ W_in + b_in)  [25000,128]@[128,32]
__global__ void k_input_proj(const float* __restrict__ x,
                             const float* __restrict__ W_in,
                             const float* __restrict__ b_in,
                             float* __restrict__ h) {
    __shared__ float Wl[FIN * CH];   // 16 KB
    __shared__ float xs[8 * FIN];    // 4 KB: 8 node rows
    int tid = threadIdx.x;
    for (int i = tid; i < FIN * CH / 4; i += 256)
        ((float4*)Wl)[i] = ((const float4*)W_in)[i];
    int nodeBase = blockIdx.x * 8;
    // 8 rows * 128 = 1024 floats = 256 float4, one per thread, coalesced
    ((float4*)xs)[tid] = ((const float4*)(x + (long)nodeBase * FIN))[tid];
    __syncthreads();
    int local = tid >> 5;   // node 0..7
    int c = tid & 31;       // channel
    float acc = b_in[c];
    const float* xr = xs + local * FIN;
#pragma unroll
    for (int k = 0; k < FIN; k++) acc = fmaf(xr[k], Wl[k * CH + c], acc);
    h[(long)(nodeBase + local) * CH + c] = lrelu(acc);
}

// ---------------- Kernel 2: fused edge-NN + matvec + scatter
// msg[e,o] = sum_c h[src[e],c] * leaky( b_edge[c*32+o] + sum_k ea[e,k]*W_edge[k, c*32+o] )
// aggr[dst[e],o] += msg[e,o]
// Block: 256 threads, 128 edges. Thread = (eslot 0..31)*(o-quad 0..7), 4 edges x 4 outs.
__global__ void __launch_bounds__(256, 2)
k_edge(const float* __restrict__ ea,
       const float* __restrict__ W_edge,
       const float* __restrict__ b_edge,
       const int* __restrict__ src,
       const int* __restrict__ dst,
       const float* __restrict__ h,
       float* __restrict__ aggr) {
    __shared__ float Wl[FE * CH * CH];   // exactly 64 KB
    int tid = threadIdx.x;
    for (int i = tid; i < FE * CH * CH / 4; i += 256)
        ((float4*)Wl)[i] = ((const float4*)W_edge)[i];
    __syncthreads();
    const float4* Wl4 = (const float4*)Wl;
    const float4* b4p = (const float4*)b_edge;

    int o4 = tid & 7;          // output quad: o = o4*4 .. o4*4+3
    int eslot = tid >> 3;      // 0..31
    int e0 = blockIdx.x * 128 + eslot * 4;

    // edge attrs for 4 edges in registers (64 VGPRs)
    float eav[4][FE];
#pragma unroll
    for (int m = 0; m < 4; m++) {
        const float4* p = (const float4*)(ea + (long)(e0 + m) * FE);
#pragma unroll
        for (int k4 = 0; k4 < 4; k4++) *((float4*)&eav[m][k4 * 4]) = p[k4];
    }
    int s[4], d[4];
#pragma unroll
    for (int m = 0; m < 4; m++) { s[m] = src[e0 + m]; d[m] = dst[e0 + m]; }

    float4 msg[4];
#pragma unroll
    for (int m = 0; m < 4; m++) msg[m] = make_float4(0.f, 0.f, 0.f, 0.f);

#pragma unroll 1
    for (int cb = 0; cb < 8; cb++) {        // channel blocks of 4
        float4 h4[4];
#pragma unroll
        for (int m = 0; m < 4; m++)
            h4[m] = *(const float4*)(h + (long)s[m] * CH + cb * 4);
#pragma unroll
        for (int cc = 0; cc < 4; cc++) {
            int c = cb * 4 + cc;
            float4 b4 = b4p[c * 8 + o4];
            float4 w[4];
#pragma unroll
            for (int m = 0; m < 4; m++) w[m] = b4;
#pragma unroll
            for (int k = 0; k < FE; k++) {
                float4 wv = Wl4[k * (CH * CH / 4) + c * 8 + o4];  // conflict-free, 8-way bcast
#pragma unroll
                for (int m = 0; m < 4; m++) {
                    w[m].x = fmaf(eav[m][k], wv.x, w[m].x);
                    w[m].y = fmaf(eav[m][k], wv.y, w[m].y);
                    w[m].z = fmaf(eav[m][k], wv.z, w[m].z);
                    w[m].w = fmaf(eav[m][k], wv.w, w[m].w);
                }
            }
#pragma unroll
            for (int m = 0; m < 4; m++) {
                float hc = ((const float*)&h4[m])[cc];
                msg[m].x = fmaf(hc, lrelu(w[m].x), msg[m].x);
                msg[m].y = fmaf(hc, lrelu(w[m].y), msg[m].y);
                msg[m].z = fmaf(hc, lrelu(w[m].z), msg[m].z);
                msg[m].w = fmaf(hc, lrelu(w[m].w), msg[m].w);
            }
        }
    }
#pragma unroll
    for (int m = 0; m < 4; m++) {
        float* p = aggr + (long)d[m] * CH + o4 * 4;
        unsafeAtomicAdd(p + 0, msg[m].x);
        unsafeAtomicAdd(p + 1, msg[m].y);
        unsafeAtomicAdd(p + 2, msg[m].z);
        unsafeAtomicAdd(p + 3, msg[m].w);
    }
}

// ---------------- Kernel 3: out = leaky(aggr + h@W_root + b_conv) @ W_out + b_out
__global__ void k_node(const float* __restrict__ aggr,
                       const float* __restrict__ h,
                       const float* __restrict__ W_root,
                       const float* __restrict__ b_conv,
                       const float* __restrict__ W_out,
                       const float* __restrict__ b_out,
                       float* __restrict__ out) {
    __shared__ float Wr[CH * CH];
    __shared__ float Wo[CH];
    __shared__ float bc[CH];
    int tid = threadIdx.x;
    for (int i = tid; i < CH * CH / 4; i += 256)
        ((float4*)Wr)[i] = ((const float4*)W_root)[i];
    if (tid < CH / 4) ((float4*)Wo)[tid] = ((const float4*)W_out)[tid];
    else if (tid >= 8 && tid < 8 + CH / 4) ((float4*)bc)[tid - 8] = ((const float4*)b_conv)[tid - 8];
    __syncthreads();
    int n = blockIdx.x * 256 + tid;
    if (n >= NN) return;
    float hr[CH], ag[CH];
#pragma unroll
    for (int i = 0; i < CH / 4; i++) {
        ((float4*)hr)[i] = ((const float4*)(h + (long)n * CH))[i];
        ((float4*)ag)[i] = ((const float4*)(aggr + (long)n * CH))[i];
    }
    float acc = b_out[0];
#pragma unroll 1
    for (int o = 0; o < CH; o++) {
        float t = ag[o] + bc[o];
#pragma unroll
        for (int c = 0; c < CH; c++) t = fmaf(hr[c], Wr[c * CH + o], t);
        acc = fmaf(lrelu(t), Wo[o], acc);
    }
    out[n] = acc;
}

extern "C" void kernel_launch(void* const* d_in, const int* in_sizes, int n_in,
                              void* d_out, int out_size, void* d_ws, size_t ws_size,
                              hipStream_t stream) {
    const float* x      = (const float*)d_in[0];
    const int*   ei     = (const int*)d_in[1];   // [2, E] (harness delivers int32)
    const float* ea     = (const float*)d_in[2];
    const float* W_in   = (const float*)d_in[3];
    const float* b_in   = (const float*)d_in[4];
    const float* W_edge = (const float*)d_in[5];
    const float* b_edge = (const float*)d_in[6];
    const float* W_root = (const float*)d_in[7];
    const float* b_conv = (const float*)d_in[8];
    const float* W_out  = (const float*)d_in[9];
    const float* b_out  = (const float*)d_in[10];
    float* out  = (float*)d_out;
    float* h    = (float*)d_ws;            // [NN, CH]
    float* aggr = h + (long)NN * CH;       // [NN, CH]

    hipMemsetAsync(aggr, 0, (size_t)NN * CH * sizeof(float), stream);
    k_input_proj<<<NN / 8, 256, 0, stream>>>(x, W_in, b_in, h);
    k_edge<<<EE / 128, 256, 0, stream>>>(ea, W_edge, b_edge, ei, ei + EE, h, aggr);
    k_node<<<(NN + 255) / 256, 256, 0, stream>>>(aggr, h, W_root, b_conv, W_out, b_out, out);
}

// Round 2
// 200.802 us; speedup vs baseline: 1.7911x; 1.7911x over previous
//
#include <hip/hip_runtime.h>

#define NN 25000
#define EE 400000
#define FIN 128
#define FE 16
#define CH 32
#define SLOPE 0.01f

typedef __attribute__((ext_vector_type(8))) short bf16x8;
typedef __attribute__((ext_vector_type(4))) float f32x4;

__device__ __forceinline__ float lrelu(float v) { return fmaxf(v, SLOPE * v); }

// float -> bf16 bits, round-to-nearest-even
__device__ __forceinline__ short f2bf(float f) {
    union { float f; unsigned u; } v; v.f = f;
    unsigned r = (v.u + 0x7fffu + ((v.u >> 16) & 1u)) >> 16;
    return (short)r;
}

// ---------------- Kernel 1: h = leaky(x @ W_in + b_in), MFMA bf16
// [25000,128] @ [128,32]. Wave = 16 nodes, block = 4 waves = 64 nodes.
__global__ void __launch_bounds__(256)
k_input_proj(const float* __restrict__ x,
             const float* __restrict__ W_in,
             const float* __restrict__ b_in,
             float* __restrict__ h) {
    // W_in transposed: Wt1[c][k], rows padded 128->136 shorts (breaks bank aliasing)
    __shared__ short Wt1[CH * 136];
    int tid = threadIdx.x;
#pragma unroll
    for (int i = 0; i < 16; i++) {
        int id = tid + 256 * i;           // id = k*32 + c
        int k = id >> 5, c = id & 31;
        Wt1[c * 136 + k] = f2bf(W_in[id]);
    }
    __syncthreads();

    int wave = tid >> 6, lane = tid & 63;
    int n16 = lane & 15, quad = lane >> 4;
    int node0 = blockIdx.x * 64 + wave * 16;

    f32x4 D[2];
#pragma unroll
    for (int ch = 0; ch < 2; ch++) {
        float bb = b_in[ch * 16 + n16];
        D[ch] = (f32x4){bb, bb, bb, bb};
    }
    int arow = node0 + n16; if (arow >= NN) arow = NN - 1;
#pragma unroll
    for (int kb = 0; kb < 4; kb++) {
        const float4* xp = (const float4*)(x + (size_t)arow * FIN + kb * 32 + quad * 8);
        float4 xa = xp[0], xb = xp[1];
        bf16x8 A = (bf16x8){f2bf(xa.x), f2bf(xa.y), f2bf(xa.z), f2bf(xa.w),
                            f2bf(xb.x), f2bf(xb.y), f2bf(xb.z), f2bf(xb.w)};
#pragma unroll
        for (int ch = 0; ch < 2; ch++) {
            bf16x8 B = *(const bf16x8*)&Wt1[(ch * 16 + n16) * 136 + kb * 32 + quad * 8];
            D[ch] = __builtin_amdgcn_mfma_f32_16x16x32_bf16(A, B, D[ch], 0, 0, 0);
        }
    }
#pragma unroll
    for (int ch = 0; ch < 2; ch++)
#pragma unroll
        for (int r = 0; r < 4; r++) {
            int nn = node0 + quad * 4 + r;
            if (nn < NN) h[(size_t)nn * CH + ch * 16 + n16] = lrelu(D[ch][r]);
        }
}

// ---------------- Kernel 2: fused edge-NN (MFMA bf16) + matvec + scatter
// Block 256 thr = 4 waves, 128 edges. Wave: 2 tiles x 16 edges.
// We[e, c*32+o] = lrelu(b_edge + ea[e,:] @ W_edge[:, c*32+o]) via MFMA
// msg[e,o] = sum_c h[src[e],c] * We[e,c,o]; atomically scatter to aggr[dst[e]].
__global__ void __launch_bounds__(256, 2)
k_edge(const float* __restrict__ ea,
       const float* __restrict__ W_edge,
       const float* __restrict__ b_edge,
       const int* __restrict__ src,
       const int* __restrict__ dst,
       const float* __restrict__ h,
       float* __restrict__ aggr) {
    __shared__ short WtL[1024 * 16];   // W_edge^T bf16: [co][k], 32 KB
    __shared__ float bseg[1024];       // b_edge, 4 KB
    __shared__ float hsL[128 * 36];    // h[src[e]] rows, padded 32->36, 18 KB
    __shared__ short zslot[8];         // 16B zero region for idle-quad B reads

    int tid = threadIdx.x;
    int e0 = blockIdx.x * 128;

    // --- stage W_edge^T (bf16) + bias
    if (tid < 8) zslot[tid] = 0;
#pragma unroll
    for (int i = 0; i < 4; i++) {
        int co = tid + 256 * i;
        short cv[16];
#pragma unroll
        for (int k = 0; k < 16; k++) cv[k] = f2bf(W_edge[k * 1024 + co]);   // coalesced per k
        ((bf16x8*)&WtL[co * 16])[0] = *(bf16x8*)&cv[0];
        ((bf16x8*)&WtL[co * 16])[1] = *(bf16x8*)&cv[8];
        bseg[co] = b_edge[co];
    }
    // --- stage h[src[e]] rows: thread = (edge e=tid>>1, half=tid&1)
    {
        int e = tid >> 1, half = tid & 1;
        int s = src[e0 + e];
        const float4* hp = (const float4*)(h + (size_t)s * CH + half * 16);
        float* wdst = &hsL[e * 36 + half * 16];
#pragma unroll
        for (int j = 0; j < 4; j++) *(float4*)(wdst + j * 4) = hp[j];
    }
    __syncthreads();

    int wave = tid >> 6, lane = tid & 63;
    int n16 = lane & 15, quad = lane >> 4;
    int t0 = wave * 32, t1 = wave * 32 + 16;   // block-local tile row bases

    // --- A fragments (ea rows, K=16 zero-padded to 32: quads 2,3 = 0)
    bf16x8 A0 = (bf16x8){0,0,0,0,0,0,0,0}, A1 = A0;
    if (quad < 2) {
        const float4* p0 = (const float4*)(ea + (size_t)(e0 + t0 + n16) * FE + quad * 8);
        const float4* p1 = (const float4*)(ea + (size_t)(e0 + t1 + n16) * FE + quad * 8);
        float4 a = p0[0], b = p0[1];
        A0 = (bf16x8){f2bf(a.x), f2bf(a.y), f2bf(a.z), f2bf(a.w),
                      f2bf(b.x), f2bf(b.y), f2bf(b.z), f2bf(b.w)};
        a = p1[0]; b = p1[1];
        A1 = (bf16x8){f2bf(a.x), f2bf(a.y), f2bf(a.z), f2bf(a.w),
                      f2bf(b.x), f2bf(b.y), f2bf(b.z), f2bf(b.w)};
    }

    f32x4 m0[2], m1[2];   // msg accumulators [ohalf] x 4 rows
    m0[0] = (f32x4){0,0,0,0}; m0[1] = m0[0]; m1[0] = m0[0]; m1[1] = m0[0];

    const short* bbase = (quad < 2) ? WtL : zslot;
    int bstride = (quad < 2) ? 1 : 0;   // idle quads always re-read zslot

#pragma unroll 1
    for (int c4 = 0; c4 < 8; c4++) {
        f32x4 hv0[4], hv1[4];
#pragma unroll
        for (int r = 0; r < 4; r++) {
            hv0[r] = *(const f32x4*)&hsL[(t0 + quad * 4 + r) * 36 + c4 * 4];
            hv1[r] = *(const f32x4*)&hsL[(t1 + quad * 4 + r) * 36 + c4 * 4];
        }
#pragma unroll
        for (int cc = 0; cc < 4; cc++) {
            int c = c4 * 4 + cc;
#pragma unroll
            for (int oh = 0; oh < 2; oh++) {
                int cb = c * 2 + oh;                 // 16-col block: co = cb*16..+16
                bf16x8 B = *(const bf16x8*)&bbase[bstride * ((cb * 16 + n16) * 16 + quad * 8)];
                float bb = bseg[cb * 16 + n16];
                f32x4 Cb = (f32x4){bb, bb, bb, bb};
                f32x4 D0 = __builtin_amdgcn_mfma_f32_16x16x32_bf16(A0, B, Cb, 0, 0, 0);
                f32x4 D1 = __builtin_amdgcn_mfma_f32_16x16x32_bf16(A1, B, Cb, 0, 0, 0);
#pragma unroll
                for (int r = 0; r < 4; r++) {
                    m0[oh][r] = fmaf(hv0[r][cc], lrelu(D0[r]), m0[oh][r]);
                    m1[oh][r] = fmaf(hv1[r][cc], lrelu(D1[r]), m1[oh][r]);
                }
            }
        }
    }

    // --- scatter: lane holds msg for edges (tX + quad*4 + r), col o = oh*16 + n16
#pragma unroll
    for (int r = 0; r < 4; r++) {
        int ed0 = dst[e0 + t0 + quad * 4 + r];
        int ed1 = dst[e0 + t1 + quad * 4 + r];
#pragma unroll
        for (int oh = 0; oh < 2; oh++) {
            unsafeAtomicAdd(&aggr[(size_t)ed0 * CH + oh * 16 + n16], m0[oh][r]);
            unsafeAtomicAdd(&aggr[(size_t)ed1 * CH + oh * 16 + n16], m1[oh][r]);
        }
    }
}

// ---------------- Kernel 3: out = leaky(aggr + h@W_root + b_conv) @ W_out + b_out
__global__ void k_node(const float* __restrict__ aggr,
                       const float* __restrict__ h,
                       const float* __restrict__ W_root,
                       const float* __restrict__ b_conv,
                       const float* __restrict__ W_out,
                       const float* __restrict__ b_out,
                       float* __restrict__ out) {
    __shared__ float Wr[CH * CH];
    __shared__ float Wo[CH];
    __shared__ float bc[CH];
    int tid = threadIdx.x;
    for (int i = tid; i < CH * CH / 4; i += 256)
        ((float4*)Wr)[i] = ((const float4*)W_root)[i];
    if (tid < CH / 4) ((float4*)Wo)[tid] = ((const float4*)W_out)[tid];
    else if (tid >= 8 && tid < 8 + CH / 4) ((float4*)bc)[tid - 8] = ((const float4*)b_conv)[tid - 8];
    __syncthreads();
    int n = blockIdx.x * 256 + tid;
    if (n >= NN) return;
    float hr[CH], ag[CH];
#pragma unroll
    for (int i = 0; i < CH / 4; i++) {
        ((float4*)hr)[i] = ((const float4*)(h + (size_t)n * CH))[i];
        ((float4*)ag)[i] = ((const float4*)(aggr + (size_t)n * CH))[i];
    }
    float acc = b_out[0];
#pragma unroll 1
    for (int o = 0; o < CH; o++) {
        float t = ag[o] + bc[o];
#pragma unroll
        for (int c = 0; c < CH; c++) t = fmaf(hr[c], Wr[c * CH + o], t);
        acc = fmaf(lrelu(t), Wo[o], acc);
    }
    out[n] = acc;
}

extern "C" void kernel_launch(void* const* d_in, const int* in_sizes, int n_in,
                              void* d_out, int out_size, void* d_ws, size_t ws_size,
                              hipStream_t stream) {
    const float* x      = (const float*)d_in[0];
    const int*   ei     = (const int*)d_in[1];
    const float* ea     = (const float*)d_in[2];
    const float* W_in   = (const float*)d_in[3];
    const float* b_in   = (const float*)d_in[4];
    const float* W_edge = (const float*)d_in[5];
    const float* b_edge = (const float*)d_in[6];
    const float* W_root = (const float*)d_in[7];
    const float* b_conv = (const float*)d_in[8];
    const float* W_out  = (const float*)d_in[9];
    const float* b_out  = (const float*)d_in[10];
    float* out  = (float*)d_out;
    float* h    = (float*)d_ws;            // [NN, CH]
    float* aggr = h + (size_t)NN * CH;     // [NN, CH]

    hipMemsetAsync(aggr, 0, (size_t)NN * CH * sizeof(float), stream);
    k_input_proj<<<(NN + 63) / 64, 256, 0, stream>>>(x, W_in, b_in, h);
    k_edge<<<EE / 128, 256, 0, stream>>>(ea, W_edge, b_edge, ei, ei + EE, h, aggr);
    k_node<<<(NN + 255) / 256, 256, 0, stream>>>(aggr, h, W_root, b_conv, W_out, b_out, out);
}